// Round 8
// baseline (475.909 us; speedup 1.0000x reference)
//
#include <hip/hip_runtime.h>
#include <hip/hip_fp16.h>

#define N_USER_C 100000
#define N_ITEM_C 100000
#define D_C 64
#define NN_C (N_USER_C + N_ITEM_C)
#define ND_C (NN_C * D_C)   /* 12,800,000 elements */

#define BSHIFT 8                                   /* 256 items per bucket */
#define NBUCKET ((N_ITEM_C + 255) >> BSHIFT)       /* 391 */
#define PB_CHUNK 8192

#define SSQ_NBLK 256
#define SCORE_NBLK 1024

typedef int      i32x2 __attribute__((ext_vector_type(2)));
typedef unsigned u32x2 __attribute__((ext_vector_type(2)));

union HPack { u32x2 u; __half2 h[2]; };

// ---- item-side CSR via bucketed counting sort ------------------------------

__global__ __launch_bounds__(256) void bucket_count_kernel(
        const int* __restrict__ acol, int* __restrict__ bcnt, int ne) {
    __shared__ int s[NBUCKET];
    for (int i = threadIdx.x; i < NBUCKET; i += 256) s[i] = 0;
    __syncthreads();
    int stride = gridDim.x * blockDim.x;
    for (int e = blockIdx.x * blockDim.x + threadIdx.x; e < ne; e += stride)
        atomicAdd(&s[(acol[e] - N_USER_C) >> BSHIFT], 1);
    __syncthreads();
    for (int i = threadIdx.x; i < NBUCKET; i += 256)
        if (s[i]) atomicAdd(&bcnt[i], s[i]);
}

__global__ void bucket_scan_kernel(const int* __restrict__ bcnt, int* __restrict__ boff,
                                   int* __restrict__ row_ptr_i, int ne) {
    __shared__ int s[512];
    int t = threadIdx.x;
    s[t] = (t < NBUCKET) ? bcnt[t] : 0;
    __syncthreads();
    for (int o = 1; o < 512; o <<= 1) {
        int v = (t >= o) ? s[t - o] : 0;
        __syncthreads();
        s[t] += v;
        __syncthreads();
    }
    if (t < NBUCKET) boff[t] = (t == 0) ? 0 : s[t - 1];
    if (t == 0) { boff[NBUCKET] = ne; row_ptr_i[N_ITEM_C] = ne; }
}

__global__ __launch_bounds__(256) void bucket_scatter_kernel(
        const int* __restrict__ arow, const int* __restrict__ acol,
        const float* __restrict__ aval, const int* __restrict__ boff,
        int* __restrict__ bfill, i32x2* __restrict__ staging, int ne) {
    __shared__ int hist[NBUCKET];
    __shared__ int base[NBUCKET];
    int nchunk = (ne + PB_CHUNK - 1) / PB_CHUNK;
    for (int ch = blockIdx.x; ch < nchunk; ch += gridDim.x) {
        int c0 = ch * PB_CHUNK;
        int c1 = c0 + PB_CHUNK; if (c1 > ne) c1 = ne;
        for (int i = threadIdx.x; i < NBUCKET; i += 256) hist[i] = 0;
        __syncthreads();
        for (int e = c0 + threadIdx.x; e < c1; e += 256)
            atomicAdd(&hist[(acol[e] - N_USER_C) >> BSHIFT], 1);
        __syncthreads();
        for (int i = threadIdx.x; i < NBUCKET; i += 256) {
            int h = hist[i];
            base[i] = h ? atomicAdd(&bfill[i], h) : 0;
            hist[i] = 0;                      // reuse as local fill
        }
        __syncthreads();
        for (int e = c0 + threadIdx.x; e < c1; e += 256) {
            int j = acol[e] - N_USER_C;
            int b = j >> BSHIFT;
            int p = atomicAdd(&hist[b], 1);
            i32x2 w; w.x = arow[e] | ((j & 255) << 24); w.y = __float_as_int(aval[e]);
            staging[boff[b] + base[b] + p] = w;
        }
        __syncthreads();
    }
}

__global__ __launch_bounds__(256) void bucket_finalize_kernel(
        const i32x2* __restrict__ staging, const int* __restrict__ boff,
        int* __restrict__ row_ptr_i, i32x2* __restrict__ csr_cv) {
    __shared__ int cnt[256];
    __shared__ int incl[256];
    int b = blockIdx.x, t = threadIdx.x;
    int s0 = boff[b], s1 = boff[b + 1];
    cnt[t] = 0;
    __syncthreads();
    for (int e = s0 + t; e < s1; e += 256)
        atomicAdd(&cnt[((unsigned)staging[e].x) >> 24], 1);
    __syncthreads();
    incl[t] = cnt[t];
    __syncthreads();
    for (int o = 1; o < 256; o <<= 1) {
        int v = (t >= o) ? incl[t - o] : 0;
        __syncthreads();
        incl[t] += v;
        __syncthreads();
    }
    int j = (b << BSHIFT) + t;
    if (j < N_ITEM_C) row_ptr_i[j] = s0 + ((t == 0) ? 0 : incl[t - 1]);
    cnt[t] = 0;                               // reuse as per-item fill
    __syncthreads();
    for (int e = s0 + t; e < s1; e += 256) {
        i32x2 w = staging[e];
        int jl = ((unsigned)w.x) >> 24;
        int p = atomicAdd(&cnt[jl], 1);
        int basej = (jl == 0) ? 0 : incl[jl - 1];
        i32x2 o2; o2.x = w.x & 0x00FFFFFF; o2.y = w.y;
        csr_cv[s0 + basej + p] = o2;
    }
}

__global__ void user_rowptr_kernel(const int* __restrict__ arow, int* __restrict__ row_ptr_u,
                                   int ne) {
    int stride = gridDim.x * blockDim.x;
    for (int e = blockIdx.x * blockDim.x + threadIdx.x; e <= ne; e += stride) {
        int prev = (e == 0) ? -1 : arow[e - 1];
        int cur = (e == ne) ? N_USER_C : arow[e];
        for (int r = prev + 1; r <= cur; ++r) row_ptr_u[r] = e;
    }
}

// Mark rows whose final embedding the loss actually reads.
__global__ void flag_kernel(const int* __restrict__ x, int* __restrict__ flags) {
    int idx = blockIdx.x * blockDim.x + threadIdx.x;
    if (idx >= 4096 * 5) return;
    int b = idx / 5, s = idx % 5;
    const int* xb = x + b * 24;
    flags[xb[s * 4]] = 1;
    flags[N_USER_C + xb[s * 4 + 1]] = 1;
}

// ---- propagation ----------------------------------------------------------
// h buffers stored fp16 (f32 accumulate). SPLIT = layer 1 (f32 weight source).

template <bool SPLIT, bool USER>
__device__ __forceinline__ float4 gather_row(
        int e0, int e1, int l, const __half* __restrict__ hin,
        const float* __restrict__ uw, const float* __restrict__ iw,
        const int* __restrict__ acol, const float* __restrict__ aval,
        const i32x2* __restrict__ csr_cv) {
    auto edge = [&](int e, int& c, float& v) {
        if (USER) {
            c = __builtin_nontemporal_load(acol + e);
            v = __builtin_nontemporal_load(aval + e);
        } else {
            i32x2 cv = __builtin_nontemporal_load(csr_cv + e);
            c = cv.x; v = __int_as_float(cv.y);
        }
    };
    float4 a0 = {0, 0, 0, 0}, a1 = {0, 0, 0, 0}, a2 = {0, 0, 0, 0}, a3 = {0, 0, 0, 0};

    if (SPLIT) {
        auto src = [&](int c) -> const float* {
            if (USER) return iw + (size_t)(c - N_USER_C) * 64 + l * 4;
            else      return uw + (size_t)c * 64 + l * 4;
        };
        int e = e0;
        for (; e + 4 <= e1; e += 4) {
            int c0, c1, c2, c3; float v0, v1, v2, v3;
            edge(e, c0, v0); edge(e + 1, c1, v1); edge(e + 2, c2, v2); edge(e + 3, c3, v3);
            float4 h0 = *reinterpret_cast<const float4*>(src(c0));
            float4 h1 = *reinterpret_cast<const float4*>(src(c1));
            float4 h2 = *reinterpret_cast<const float4*>(src(c2));
            float4 h3 = *reinterpret_cast<const float4*>(src(c3));
            a0.x += v0 * h0.x; a0.y += v0 * h0.y; a0.z += v0 * h0.z; a0.w += v0 * h0.w;
            a1.x += v1 * h1.x; a1.y += v1 * h1.y; a1.z += v1 * h1.z; a1.w += v1 * h1.w;
            a2.x += v2 * h2.x; a2.y += v2 * h2.y; a2.z += v2 * h2.z; a2.w += v2 * h2.w;
            a3.x += v3 * h3.x; a3.y += v3 * h3.y; a3.z += v3 * h3.z; a3.w += v3 * h3.w;
        }
        for (; e < e1; ++e) {
            int c0; float v0;
            edge(e, c0, v0);
            float4 h0 = *reinterpret_cast<const float4*>(src(c0));
            a0.x += v0 * h0.x; a0.y += v0 * h0.y; a0.z += v0 * h0.z; a0.w += v0 * h0.w;
        }
    } else {
        auto srcH = [&](int c) -> const u32x2* {
            return reinterpret_cast<const u32x2*>(hin + (size_t)c * 64 + l * 4);
        };
        auto fma4 = [&](float4& a, float v, const HPack& p) {
            float2 f01 = __half22float2(p.h[0]);
            float2 f23 = __half22float2(p.h[1]);
            a.x += v * f01.x; a.y += v * f01.y; a.z += v * f23.x; a.w += v * f23.y;
        };
        int e = e0;
        for (; e + 4 <= e1; e += 4) {
            int c0, c1, c2, c3; float v0, v1, v2, v3;
            edge(e, c0, v0); edge(e + 1, c1, v1); edge(e + 2, c2, v2); edge(e + 3, c3, v3);
            HPack p0, p1, p2, p3;
            p0.u = *srcH(c0); p1.u = *srcH(c1); p2.u = *srcH(c2); p3.u = *srcH(c3);
            fma4(a0, v0, p0); fma4(a1, v1, p1); fma4(a2, v2, p2); fma4(a3, v3, p3);
        }
        for (; e < e1; ++e) {
            int c0; float v0;
            edge(e, c0, v0);
            HPack p0; p0.u = *srcH(c0);
            fma4(a0, v0, p0);
        }
    }
    float4 acc;
    acc.x = (a0.x + a1.x) + (a2.x + a3.x);
    acc.y = (a0.y + a1.y) + (a2.y + a3.y);
    acc.z = (a0.z + a1.z) + (a2.z + a3.z);
    acc.w = (a0.w + a1.w) + (a2.w + a3.w);
    return acc;
}

template <bool SPLIT, bool SPARSE>
__global__ __launch_bounds__(256) void spmv_kernel(
        const __half* __restrict__ hin, const float* __restrict__ uw,
        const float* __restrict__ iw, __half* __restrict__ hout,
        const int* __restrict__ row_ptr_u, const int* __restrict__ row_ptr_i,
        const int* __restrict__ acol, const float* __restrict__ aval,
        const i32x2* __restrict__ csr_cv, const int* __restrict__ flags) {
    int gid = blockIdx.x * blockDim.x + threadIdx.x;
    int r = gid >> 4;
    int l = gid & 15;
    if (r >= NN_C) return;
    if (SPARSE && flags[r] == 0) return;

    float4 acc;
    if (r < N_USER_C) {
        int e0 = row_ptr_u[r], e1 = row_ptr_u[r + 1];
        acc = gather_row<SPLIT, true>(e0, e1, l, hin, uw, iw, acol, aval, csr_cv);
    } else {
        int rr = r - N_USER_C;
        int e0 = row_ptr_i[rr], e1 = row_ptr_i[rr + 1];
        acc = gather_row<SPLIT, false>(e0, e1, l, hin, uw, iw, acol, aval, csr_cv);
    }

    float ss = acc.x * acc.x + acc.y * acc.y + acc.z * acc.z + acc.w * acc.w;
    ss += __shfl_xor(ss, 1);
    ss += __shfl_xor(ss, 2);
    ss += __shfl_xor(ss, 4);
    ss += __shfl_xor(ss, 8);
    float scale = 1.0f / fmaxf(sqrtf(ss), 1e-12f);

    HPack o;
    o.h[0] = __float22half2_rn(make_float2(acc.x * scale, acc.y * scale));
    o.h[1] = __float22half2_rn(make_float2(acc.z * scale, acc.w * scale));
    __builtin_nontemporal_store(o.u,
        reinterpret_cast<u32x2*>(hout + (size_t)r * 64 + l * 4));
}

// ---- losses (two-stage, atomic-free) ---------------------------------------

__global__ void ssq_kernel(const float4* __restrict__ uw, const float4* __restrict__ iw,
                           float2* __restrict__ partial_sq, int n4) {
    __shared__ float s_u[4], s_i[4];
    int stride = gridDim.x * blockDim.x;
    float su = 0.f, si = 0.f;
    int tot = 2 * n4;
    for (int i = blockIdx.x * blockDim.x + threadIdx.x; i < tot; i += stride) {
        float4 v = (i < n4) ? uw[i] : iw[i - n4];
        float d = v.x * v.x + v.y * v.y + v.z * v.z + v.w * v.w;
        if (i < n4) su += d; else si += d;
    }
    #pragma unroll
    for (int o = 1; o < 64; o <<= 1) { su += __shfl_xor(su, o); si += __shfl_xor(si, o); }
    int w = threadIdx.x >> 6;
    if ((threadIdx.x & 63) == 0) { s_u[w] = su; s_i[w] = si; }
    __syncthreads();
    if (threadIdx.x == 0) {
        float tu = s_u[0] + s_u[1] + s_u[2] + s_u[3];
        float ti = s_i[0] + s_i[1] + s_i[2] + s_i[3];
        partial_sq[blockIdx.x] = make_float2(tu, ti);
    }
}

__global__ void score_kernel(const int* __restrict__ x,
                             const float* __restrict__ uw, const float* __restrict__ iw,
                             const __half* __restrict__ h1, const __half* __restrict__ h2,
                             const __half* __restrict__ h3, float* __restrict__ partial_loss) {
    __shared__ float s_l[4];
    int wave = threadIdx.x >> 6;
    int lane = threadIdx.x & 63;
    int b = blockIdx.x * 4 + wave;
    const int* xb = x + b * 24;          // (B, S=6, 4) int32

    auto emb = [&](int r) -> float {
        size_t o = (size_t)r * 64 + lane;
        float base = (r < N_USER_C) ? uw[o] : iw[o - (size_t)N_USER_C * 64];
        return base + 2.0f * __half2float(h1[o]) + 1.5f * __half2float(h2[o])
                    + (4.0f / 3.0f) * __half2float(h3[o]);
    };

    float t = emb(xb[0]) * emb(N_USER_C + xb[1]);
    #pragma unroll
    for (int s = 1; s <= 4; ++s)
        t -= emb(xb[s * 4]) * emb(N_USER_C + xb[s * 4 + 1]);

    #pragma unroll
    for (int o = 1; o < 64; o <<= 1) t += __shfl_xor(t, o);
    if (lane == 0) {
        float sig = 1.0f / (1.0f + expf(-t));
        s_l[wave] = -logf(1e-10f + sig);
    }
    __syncthreads();
    if (threadIdx.x == 0)
        partial_loss[blockIdx.x] = s_l[0] + s_l[1] + s_l[2] + s_l[3];
}

__global__ void final_kernel(const float2* __restrict__ partial_sq,
                             const float* __restrict__ partial_loss,
                             float* __restrict__ out) {
    __shared__ float s_u[4], s_i[4], s_l[4];
    int t = threadIdx.x;
    int w = t >> 6, lane = t & 63;

    float2 p = partial_sq[t];            // SSQ_NBLK == 256 == blockDim
    float su = p.x, si = p.y;
    float lo = 0.f;
    #pragma unroll
    for (int k = 0; k < SCORE_NBLK / 256; ++k) lo += partial_loss[t + k * 256];

    #pragma unroll
    for (int o = 1; o < 64; o <<= 1) {
        su += __shfl_xor(su, o);
        si += __shfl_xor(si, o);
        lo += __shfl_xor(lo, o);
    }
    if (lane == 0) { s_u[w] = su; s_i[w] = si; s_l[w] = lo; }
    __syncthreads();
    if (t == 0) {
        float tu = s_u[0] + s_u[1] + s_u[2] + s_u[3];
        float ti = s_i[0] + s_i[1] + s_i[2] + s_i[3];
        float tl = s_l[0] + s_l[1] + s_l[2] + s_l[3];
        float bpr = tl / 4096.0f;
        float emb_loss = (sqrtf(tu) + sqrtf(ti)) / (float)N_ITEM_C;
        out[0] = bpr + 1e-4f * emb_loss;
    }
}

// ---- launch ---------------------------------------------------------------

extern "C" void kernel_launch(void* const* d_in, const int* in_sizes, int n_in,
                              void* d_out, int out_size, void* d_ws, size_t ws_size,
                              hipStream_t stream) {
    const int*   x    = (const int*)d_in[0];
    const float* uw   = (const float*)d_in[1];
    const float* iw   = (const float*)d_in[2];
    const int*   arow = (const int*)d_in[3];
    const int*   acol = (const int*)d_in[4];
    const float* aval = (const float*)d_in[5];
    int nnz = in_sizes[3];
    int ne = nnz / 2;                     // edges per half

    char* ws = (char*)d_ws;
    size_t off = 0;
    auto alloc = [&](size_t bytes) -> void* {
        void* p = ws + off;
        off += bytes;
        off = (off + 255) & ~(size_t)255;
        return p;
    };
    __half* h1        = (__half*)alloc((size_t)ND_C * 2);
    __half* h2        = (__half*)alloc((size_t)ND_C * 2);
    __half* h3        = (__half*)alloc((size_t)ND_C * 2);
    i32x2*  csr_cv    = (i32x2*)alloc((size_t)ne * 8);
    int*    row_ptr_u = (int*)alloc((size_t)(N_USER_C + 1) * 4);
    int*    row_ptr_i = (int*)alloc((size_t)(N_ITEM_C + 1) * 4);
    int*    flags     = (int*)alloc((size_t)NN_C * 4);
    int*    bcnt      = (int*)alloc((size_t)NBUCKET * 4);
    int*    bfill     = (int*)alloc((size_t)NBUCKET * 4);
    int*    boff      = (int*)alloc((size_t)(NBUCKET + 1) * 4);
    float2* psq       = (float2*)alloc((size_t)SSQ_NBLK * 8);
    float*  ploss     = (float*)alloc((size_t)SCORE_NBLK * 4);
    // staging aliases h3 (ne*8 = 12.8MB <= ND_C*2 = 25.6MB), consumed by
    // bucket_finalize before layer-3 spmv writes h3 (stream-ordered).
    i32x2*  staging   = (i32x2*)h3;

    hipMemsetAsync(bcnt, 0, (size_t)NBUCKET * 4, stream);
    hipMemsetAsync(bfill, 0, (size_t)NBUCKET * 4, stream);
    hipMemsetAsync(flags, 0, (size_t)NN_C * 4, stream);

    const int eb = 256;
    int egrid = (ne + eb - 1) / eb;
    if (egrid > 4096) egrid = 4096;

    bucket_count_kernel<<<256, 256, 0, stream>>>(acol, bcnt, ne);
    bucket_scan_kernel<<<1, 512, 0, stream>>>(bcnt, boff, row_ptr_i, ne);
    int nchunk = (ne + PB_CHUNK - 1) / PB_CHUNK;
    bucket_scatter_kernel<<<nchunk, 256, 0, stream>>>(arow, acol, aval, boff,
                                                      bfill, staging, ne);
    bucket_finalize_kernel<<<NBUCKET, 256, 0, stream>>>(staging, boff, row_ptr_i, csr_cv);
    user_rowptr_kernel<<<egrid, eb, 0, stream>>>(arow, row_ptr_u, ne);
    flag_kernel<<<80, 256, 0, stream>>>(x, flags);

    int grid = (NN_C * 16 + 255) / 256;   // 12500 blocks
    spmv_kernel<true, false><<<grid, 256, 0, stream>>>(nullptr, uw, iw, h1,
        row_ptr_u, row_ptr_i, acol, aval, csr_cv, flags);
    spmv_kernel<false, false><<<grid, 256, 0, stream>>>(h1, uw, iw, h2,
        row_ptr_u, row_ptr_i, acol, aval, csr_cv, flags);
    spmv_kernel<false, true><<<grid, 256, 0, stream>>>(h2, uw, iw, h3,
        row_ptr_u, row_ptr_i, acol, aval, csr_cv, flags);

    ssq_kernel<<<SSQ_NBLK, 256, 0, stream>>>((const float4*)uw, (const float4*)iw,
                                             psq, N_USER_C * D_C / 4);
    score_kernel<<<SCORE_NBLK, 256, 0, stream>>>(x, uw, iw, h1, h2, h3, ploss);
    final_kernel<<<1, 256, 0, stream>>>(psq, ploss, (float*)d_out);
}

// Round 9
// 394.512 us; speedup vs baseline: 1.2063x; 1.2063x over previous
//
#include <hip/hip_runtime.h>
#include <hip/hip_fp16.h>

#define N_USER_C 100000
#define N_ITEM_C 100000
#define D_C 64
#define NN_C (N_USER_C + N_ITEM_C)
#define ND_C (NN_C * D_C)   /* 12,800,000 elements */

#define BSHIFT 8                                   /* 256 items per bucket */
#define NBUCKET ((N_ITEM_C + 255) >> BSHIFT)       /* 391 */
#define PB_CHUNK 8192

#define SSQ_NBLK 256
#define SCORE_NBLK 1024

typedef int      i32x2 __attribute__((ext_vector_type(2)));
typedef unsigned u32x2 __attribute__((ext_vector_type(2)));

union HPack { u32x2 u; __half2 h[2]; };

// ---- item-side CSR via bucketed counting sort ------------------------------

__global__ __launch_bounds__(256) void bucket_count_kernel(
        const int* __restrict__ acol, int* __restrict__ bcnt, int ne) {
    __shared__ int s[NBUCKET];
    for (int i = threadIdx.x; i < NBUCKET; i += 256) s[i] = 0;
    __syncthreads();
    int stride = gridDim.x * blockDim.x;
    for (int e = blockIdx.x * blockDim.x + threadIdx.x; e < ne; e += stride)
        atomicAdd(&s[(acol[e] - N_USER_C) >> BSHIFT], 1);
    __syncthreads();
    for (int i = threadIdx.x; i < NBUCKET; i += 256)
        if (s[i]) atomicAdd(&bcnt[i], s[i]);
}

__global__ void bucket_scan_kernel(const int* __restrict__ bcnt, int* __restrict__ boff,
                                   int* __restrict__ row_ptr_i, int ne) {
    __shared__ int s[512];
    int t = threadIdx.x;
    s[t] = (t < NBUCKET) ? bcnt[t] : 0;
    __syncthreads();
    for (int o = 1; o < 512; o <<= 1) {
        int v = (t >= o) ? s[t - o] : 0;
        __syncthreads();
        s[t] += v;
        __syncthreads();
    }
    if (t < NBUCKET) boff[t] = (t == 0) ? 0 : s[t - 1];
    if (t == 0) { boff[NBUCKET] = ne; row_ptr_i[N_ITEM_C] = ne; }
}

__global__ __launch_bounds__(256) void bucket_scatter_kernel(
        const int* __restrict__ arow, const int* __restrict__ acol,
        const float* __restrict__ aval, const int* __restrict__ boff,
        int* __restrict__ bfill, i32x2* __restrict__ staging, int ne) {
    __shared__ int hist[NBUCKET];
    __shared__ int base[NBUCKET];
    int nchunk = (ne + PB_CHUNK - 1) / PB_CHUNK;
    for (int ch = blockIdx.x; ch < nchunk; ch += gridDim.x) {
        int c0 = ch * PB_CHUNK;
        int c1 = c0 + PB_CHUNK; if (c1 > ne) c1 = ne;
        for (int i = threadIdx.x; i < NBUCKET; i += 256) hist[i] = 0;
        __syncthreads();
        for (int e = c0 + threadIdx.x; e < c1; e += 256)
            atomicAdd(&hist[(acol[e] - N_USER_C) >> BSHIFT], 1);
        __syncthreads();
        for (int i = threadIdx.x; i < NBUCKET; i += 256) {
            int h = hist[i];
            base[i] = h ? atomicAdd(&bfill[i], h) : 0;
            hist[i] = 0;                      // reuse as local fill
        }
        __syncthreads();
        for (int e = c0 + threadIdx.x; e < c1; e += 256) {
            int j = acol[e] - N_USER_C;
            int b = j >> BSHIFT;
            int p = atomicAdd(&hist[b], 1);
            i32x2 w; w.x = arow[e] | ((j & 255) << 24); w.y = __float_as_int(aval[e]);
            staging[boff[b] + base[b] + p] = w;
        }
        __syncthreads();
    }
}

__global__ __launch_bounds__(256) void bucket_finalize_kernel(
        const i32x2* __restrict__ staging, const int* __restrict__ boff,
        int* __restrict__ row_ptr_i, i32x2* __restrict__ csr_cv) {
    __shared__ int cnt[256];
    __shared__ int incl[256];
    int b = blockIdx.x, t = threadIdx.x;
    int s0 = boff[b], s1 = boff[b + 1];
    cnt[t] = 0;
    __syncthreads();
    for (int e = s0 + t; e < s1; e += 256)
        atomicAdd(&cnt[((unsigned)staging[e].x) >> 24], 1);
    __syncthreads();
    incl[t] = cnt[t];
    __syncthreads();
    for (int o = 1; o < 256; o <<= 1) {
        int v = (t >= o) ? incl[t - o] : 0;
        __syncthreads();
        incl[t] += v;
        __syncthreads();
    }
    int j = (b << BSHIFT) + t;
    if (j < N_ITEM_C) row_ptr_i[j] = s0 + ((t == 0) ? 0 : incl[t - 1]);
    cnt[t] = 0;                               // reuse as per-item fill
    __syncthreads();
    for (int e = s0 + t; e < s1; e += 256) {
        i32x2 w = staging[e];
        int jl = ((unsigned)w.x) >> 24;
        int p = atomicAdd(&cnt[jl], 1);
        int basej = (jl == 0) ? 0 : incl[jl - 1];
        i32x2 o2; o2.x = w.x & 0x00FFFFFF; o2.y = w.y;
        csr_cv[s0 + basej + p] = o2;
    }
}

__global__ void user_rowptr_kernel(const int* __restrict__ arow, int* __restrict__ row_ptr_u,
                                   int ne) {
    int stride = gridDim.x * blockDim.x;
    for (int e = blockIdx.x * blockDim.x + threadIdx.x; e <= ne; e += stride) {
        int prev = (e == 0) ? -1 : arow[e - 1];
        int cur = (e == ne) ? N_USER_C : arow[e];
        for (int r = prev + 1; r <= cur; ++r) row_ptr_u[r] = e;
    }
}

// Mark rows whose final embedding the loss actually reads.
__global__ void flag_kernel(const int* __restrict__ x, int* __restrict__ flags) {
    int idx = blockIdx.x * blockDim.x + threadIdx.x;
    if (idx >= 4096 * 5) return;
    int b = idx / 5, s = idx % 5;
    const int* xb = x + b * 24;
    flags[xb[s * 4]] = 1;
    flags[N_USER_C + xb[s * 4 + 1]] = 1;
}

// f32 weights -> packed fp16 table wtab[NN][64]. 8 elems/thread.
__global__ __launch_bounds__(256) void conv_kernel(
        const float4* __restrict__ uw, const float4* __restrict__ iw,
        u32x2* __restrict__ wtab) {
    int stride = gridDim.x * blockDim.x;
    int tot = ND_C / 8;                    /* 1.6M packs of 8 */
    int nu = N_USER_C * D_C / 8;
    for (int i = blockIdx.x * blockDim.x + threadIdx.x; i < tot; i += stride) {
        const float4* s = (i < nu) ? (uw + (size_t)i * 2) : (iw + (size_t)(i - nu) * 2);
        float4 f0 = s[0], f1 = s[1];
        HPack a, b;
        a.h[0] = __float22half2_rn(make_float2(f0.x, f0.y));
        a.h[1] = __float22half2_rn(make_float2(f0.z, f0.w));
        b.h[0] = __float22half2_rn(make_float2(f1.x, f1.y));
        b.h[1] = __float22half2_rn(make_float2(f1.z, f1.w));
        wtab[(size_t)i * 2] = a.u;
        wtab[(size_t)i * 2 + 1] = b.u;
    }
}

// ---- propagation ----------------------------------------------------------
// All layers gather fp16 rows (layer 1 from wtab). f32 accumulate.

template <bool USER>
__device__ __forceinline__ float4 gather_row(
        int e0, int e1, int l, const __half* __restrict__ hin,
        const int* __restrict__ acol, const float* __restrict__ aval,
        const i32x2* __restrict__ csr_cv) {
    auto edge = [&](int e, int& c, float& v) {
        if (USER) { c = acol[e]; v = aval[e]; }       // c is global col (>= N_USER)
        else { i32x2 cv = csr_cv[e]; c = cv.x; v = __int_as_float(cv.y); }
    };
    auto srcH = [&](int c) -> const u32x2* {
        return reinterpret_cast<const u32x2*>(hin + (size_t)c * 64 + l * 4);
    };
    auto fma4 = [&](float4& a, float v, const HPack& p) {
        float2 f01 = __half22float2(p.h[0]);
        float2 f23 = __half22float2(p.h[1]);
        a.x += v * f01.x; a.y += v * f01.y; a.z += v * f23.x; a.w += v * f23.y;
    };
    float4 a0 = {0, 0, 0, 0}, a1 = {0, 0, 0, 0}, a2 = {0, 0, 0, 0}, a3 = {0, 0, 0, 0};
    int e = e0;
    for (; e + 4 <= e1; e += 4) {
        int c0, c1, c2, c3; float v0, v1, v2, v3;
        edge(e, c0, v0); edge(e + 1, c1, v1); edge(e + 2, c2, v2); edge(e + 3, c3, v3);
        HPack p0, p1, p2, p3;
        p0.u = *srcH(c0); p1.u = *srcH(c1); p2.u = *srcH(c2); p3.u = *srcH(c3);
        fma4(a0, v0, p0); fma4(a1, v1, p1); fma4(a2, v2, p2); fma4(a3, v3, p3);
    }
    for (; e < e1; ++e) {
        int c0; float v0;
        edge(e, c0, v0);
        HPack p0; p0.u = *srcH(c0);
        fma4(a0, v0, p0);
    }
    float4 acc;
    acc.x = (a0.x + a1.x) + (a2.x + a3.x);
    acc.y = (a0.y + a1.y) + (a2.y + a3.y);
    acc.z = (a0.z + a1.z) + (a2.z + a3.z);
    acc.w = (a0.w + a1.w) + (a2.w + a3.w);
    return acc;
}

template <bool SPARSE>
__global__ __launch_bounds__(256) void spmv_kernel(
        const __half* __restrict__ hin, __half* __restrict__ hout,
        const int* __restrict__ row_ptr_u, const int* __restrict__ row_ptr_i,
        const int* __restrict__ acol, const float* __restrict__ aval,
        const i32x2* __restrict__ csr_cv, const int* __restrict__ flags) {
    int gid = blockIdx.x * blockDim.x + threadIdx.x;
    int r = gid >> 4;
    int l = gid & 15;
    if (r >= NN_C) return;
    if (SPARSE && flags[r] == 0) return;

    float4 acc;
    if (r < N_USER_C) {
        int e0 = row_ptr_u[r], e1 = row_ptr_u[r + 1];
        acc = gather_row<true>(e0, e1, l, hin, acol, aval, csr_cv);
    } else {
        int rr = r - N_USER_C;
        int e0 = row_ptr_i[rr], e1 = row_ptr_i[rr + 1];
        acc = gather_row<false>(e0, e1, l, hin, acol, aval, csr_cv);
    }

    float ss = acc.x * acc.x + acc.y * acc.y + acc.z * acc.z + acc.w * acc.w;
    ss += __shfl_xor(ss, 1);
    ss += __shfl_xor(ss, 2);
    ss += __shfl_xor(ss, 4);
    ss += __shfl_xor(ss, 8);
    float scale = 1.0f / fmaxf(sqrtf(ss), 1e-12f);

    HPack o;
    o.h[0] = __float22half2_rn(make_float2(acc.x * scale, acc.y * scale));
    o.h[1] = __float22half2_rn(make_float2(acc.z * scale, acc.w * scale));
    *reinterpret_cast<u32x2*>(hout + (size_t)r * 64 + l * 4) = o.u;
}

// ---- losses (two-stage, atomic-free) ---------------------------------------

__global__ void ssq_kernel(const float4* __restrict__ uw, const float4* __restrict__ iw,
                           float2* __restrict__ partial_sq, int n4) {
    __shared__ float s_u[4], s_i[4];
    int stride = gridDim.x * blockDim.x;
    float su = 0.f, si = 0.f;
    int tot = 2 * n4;
    for (int i = blockIdx.x * blockDim.x + threadIdx.x; i < tot; i += stride) {
        float4 v = (i < n4) ? uw[i] : iw[i - n4];
        float d = v.x * v.x + v.y * v.y + v.z * v.z + v.w * v.w;
        if (i < n4) su += d; else si += d;
    }
    #pragma unroll
    for (int o = 1; o < 64; o <<= 1) { su += __shfl_xor(su, o); si += __shfl_xor(si, o); }
    int w = threadIdx.x >> 6;
    if ((threadIdx.x & 63) == 0) { s_u[w] = su; s_i[w] = si; }
    __syncthreads();
    if (threadIdx.x == 0) {
        float tu = s_u[0] + s_u[1] + s_u[2] + s_u[3];
        float ti = s_i[0] + s_i[1] + s_i[2] + s_i[3];
        partial_sq[blockIdx.x] = make_float2(tu, ti);
    }
}

__global__ void score_kernel(const int* __restrict__ x,
                             const float* __restrict__ uw, const float* __restrict__ iw,
                             const __half* __restrict__ h1, const __half* __restrict__ h2,
                             const __half* __restrict__ h3, float* __restrict__ partial_loss) {
    __shared__ float s_l[4];
    int wave = threadIdx.x >> 6;
    int lane = threadIdx.x & 63;
    int b = blockIdx.x * 4 + wave;
    const int* xb = x + b * 24;          // (B, S=6, 4) int32

    auto emb = [&](int r) -> float {
        size_t o = (size_t)r * 64 + lane;
        float base = (r < N_USER_C) ? uw[o] : iw[o - (size_t)N_USER_C * 64];
        return base + 2.0f * __half2float(h1[o]) + 1.5f * __half2float(h2[o])
                    + (4.0f / 3.0f) * __half2float(h3[o]);
    };

    float t = emb(xb[0]) * emb(N_USER_C + xb[1]);
    #pragma unroll
    for (int s = 1; s <= 4; ++s)
        t -= emb(xb[s * 4]) * emb(N_USER_C + xb[s * 4 + 1]);

    #pragma unroll
    for (int o = 1; o < 64; o <<= 1) t += __shfl_xor(t, o);
    if (lane == 0) {
        float sig = 1.0f / (1.0f + expf(-t));
        s_l[wave] = -logf(1e-10f + sig);
    }
    __syncthreads();
    if (threadIdx.x == 0)
        partial_loss[blockIdx.x] = s_l[0] + s_l[1] + s_l[2] + s_l[3];
}

__global__ void final_kernel(const float2* __restrict__ partial_sq,
                             const float* __restrict__ partial_loss,
                             float* __restrict__ out) {
    __shared__ float s_u[4], s_i[4], s_l[4];
    int t = threadIdx.x;
    int w = t >> 6, lane = t & 63;

    float2 p = partial_sq[t];            // SSQ_NBLK == 256 == blockDim
    float su = p.x, si = p.y;
    float lo = 0.f;
    #pragma unroll
    for (int k = 0; k < SCORE_NBLK / 256; ++k) lo += partial_loss[t + k * 256];

    #pragma unroll
    for (int o = 1; o < 64; o <<= 1) {
        su += __shfl_xor(su, o);
        si += __shfl_xor(si, o);
        lo += __shfl_xor(lo, o);
    }
    if (lane == 0) { s_u[w] = su; s_i[w] = si; s_l[w] = lo; }
    __syncthreads();
    if (t == 0) {
        float tu = s_u[0] + s_u[1] + s_u[2] + s_u[3];
        float ti = s_i[0] + s_i[1] + s_i[2] + s_i[3];
        float tl = s_l[0] + s_l[1] + s_l[2] + s_l[3];
        float bpr = tl / 4096.0f;
        float emb_loss = (sqrtf(tu) + sqrtf(ti)) / (float)N_ITEM_C;
        out[0] = bpr + 1e-4f * emb_loss;
    }
}

// ---- launch ---------------------------------------------------------------

extern "C" void kernel_launch(void* const* d_in, const int* in_sizes, int n_in,
                              void* d_out, int out_size, void* d_ws, size_t ws_size,
                              hipStream_t stream) {
    const int*   x    = (const int*)d_in[0];
    const float* uw   = (const float*)d_in[1];
    const float* iw   = (const float*)d_in[2];
    const int*   arow = (const int*)d_in[3];
    const int*   acol = (const int*)d_in[4];
    const float* aval = (const float*)d_in[5];
    int nnz = in_sizes[3];
    int ne = nnz / 2;                     // edges per half

    char* ws = (char*)d_ws;
    size_t off = 0;
    auto alloc = [&](size_t bytes) -> void* {
        void* p = ws + off;
        off += bytes;
        off = (off + 255) & ~(size_t)255;
        return p;
    };
    __half* wtab      = (__half*)alloc((size_t)ND_C * 2);
    __half* h1        = (__half*)alloc((size_t)ND_C * 2);
    __half* h2        = (__half*)alloc((size_t)ND_C * 2);
    __half* h3        = (__half*)alloc((size_t)ND_C * 2);
    i32x2*  csr_cv    = (i32x2*)alloc((size_t)ne * 8);
    int*    row_ptr_u = (int*)alloc((size_t)(N_USER_C + 1) * 4);
    int*    row_ptr_i = (int*)alloc((size_t)(N_ITEM_C + 1) * 4);
    int*    flags     = (int*)alloc((size_t)NN_C * 4);
    int*    bcnt      = (int*)alloc((size_t)NBUCKET * 4);
    int*    bfill     = (int*)alloc((size_t)NBUCKET * 4);
    int*    boff      = (int*)alloc((size_t)(NBUCKET + 1) * 4);
    float2* psq       = (float2*)alloc((size_t)SSQ_NBLK * 8);
    float*  ploss     = (float*)alloc((size_t)SCORE_NBLK * 4);
    // staging aliases h3 (ne*8 = 12.8MB <= ND_C*2 = 25.6MB), consumed by
    // bucket_finalize before layer-3 spmv writes h3 (stream-ordered).
    i32x2*  staging   = (i32x2*)h3;

    hipMemsetAsync(bcnt, 0, (size_t)NBUCKET * 4, stream);
    hipMemsetAsync(bfill, 0, (size_t)NBUCKET * 4, stream);
    hipMemsetAsync(flags, 0, (size_t)NN_C * 4, stream);

    const int eb = 256;
    int egrid = (ne + eb - 1) / eb;
    if (egrid > 4096) egrid = 4096;

    conv_kernel<<<2048, 256, 0, stream>>>((const float4*)uw, (const float4*)iw,
                                          (u32x2*)wtab);
    bucket_count_kernel<<<256, 256, 0, stream>>>(acol, bcnt, ne);
    bucket_scan_kernel<<<1, 512, 0, stream>>>(bcnt, boff, row_ptr_i, ne);
    int nchunk = (ne + PB_CHUNK - 1) / PB_CHUNK;
    bucket_scatter_kernel<<<nchunk, 256, 0, stream>>>(arow, acol, aval, boff,
                                                      bfill, staging, ne);
    bucket_finalize_kernel<<<NBUCKET, 256, 0, stream>>>(staging, boff, row_ptr_i, csr_cv);
    user_rowptr_kernel<<<egrid, eb, 0, stream>>>(arow, row_ptr_u, ne);
    flag_kernel<<<80, 256, 0, stream>>>(x, flags);

    int grid = (NN_C * 16 + 255) / 256;   // 12500 blocks
    spmv_kernel<false><<<grid, 256, 0, stream>>>(wtab, h1,
        row_ptr_u, row_ptr_i, acol, aval, csr_cv, flags);
    spmv_kernel<false><<<grid, 256, 0, stream>>>(h1, h2,
        row_ptr_u, row_ptr_i, acol, aval, csr_cv, flags);
    spmv_kernel<true><<<grid, 256, 0, stream>>>(h2, h3,
        row_ptr_u, row_ptr_i, acol, aval, csr_cv, flags);

    ssq_kernel<<<SSQ_NBLK, 256, 0, stream>>>((const float4*)uw, (const float4*)iw,
                                             psq, N_USER_C * D_C / 4);
    score_kernel<<<SCORE_NBLK, 256, 0, stream>>>(x, uw, iw, h1, h2, h3, ploss);
    final_kernel<<<1, 256, 0, stream>>>(psq, ploss, (float*)d_out);
}

// Round 10
// 367.816 us; speedup vs baseline: 1.2939x; 1.0726x over previous
//
#include <hip/hip_runtime.h>
#include <hip/hip_fp16.h>

#define N_USER_C 100000
#define N_ITEM_C 100000
#define D_C 64
#define NN_C (N_USER_C + N_ITEM_C)
#define ND_C (NN_C * D_C)   /* 12,800,000 elements */

#define BSHIFT 8                                   /* 256 items per bucket */
#define NBUCKET ((N_ITEM_C + 255) >> BSHIFT)       /* 391 */
#define PB_CHUNK 8192

#define SSQ_NBLK 256
#define SCORE_NBLK 1024

typedef unsigned u32x4 __attribute__((ext_vector_type(4)));

union HP8 { u32x4 u; __half2 h[4]; };

// ---- item-side CSR (col-only payload) via bucketed counting sort -----------
// Built from the FIRST half of the edge list (second half is the mirror).
// Edge values are NOT stored: normalization folds dinv_c into the table rows
// and dinv_r cancels in the row-normalize.

__global__ __launch_bounds__(256) void bucket_count_kernel(
        const int* __restrict__ acol, int* __restrict__ bcnt, int ne) {
    __shared__ int s[NBUCKET];
    for (int i = threadIdx.x; i < NBUCKET; i += 256) s[i] = 0;
    __syncthreads();
    int stride = gridDim.x * blockDim.x;
    for (int e = blockIdx.x * blockDim.x + threadIdx.x; e < ne; e += stride)
        atomicAdd(&s[(acol[e] - N_USER_C) >> BSHIFT], 1);
    __syncthreads();
    for (int i = threadIdx.x; i < NBUCKET; i += 256)
        if (s[i]) atomicAdd(&bcnt[i], s[i]);
}

__global__ void bucket_scan_kernel(const int* __restrict__ bcnt, int* __restrict__ boff,
                                   int* __restrict__ row_ptr_i, int ne) {
    __shared__ int s[512];
    int t = threadIdx.x;
    s[t] = (t < NBUCKET) ? bcnt[t] : 0;
    __syncthreads();
    for (int o = 1; o < 512; o <<= 1) {
        int v = (t >= o) ? s[t - o] : 0;
        __syncthreads();
        s[t] += v;
        __syncthreads();
    }
    if (t < NBUCKET) boff[t] = (t == 0) ? 0 : s[t - 1];
    if (t == 0) { boff[NBUCKET] = ne; row_ptr_i[N_ITEM_C] = ne; }
}

// staging word = user(17b) | item_local(8b)<<24
__global__ __launch_bounds__(256) void bucket_scatter_kernel(
        const int* __restrict__ arow, const int* __restrict__ acol,
        const int* __restrict__ boff, int* __restrict__ bfill,
        int* __restrict__ staging, int ne) {
    __shared__ int hist[NBUCKET];
    __shared__ int base[NBUCKET];
    int nchunk = (ne + PB_CHUNK - 1) / PB_CHUNK;
    for (int ch = blockIdx.x; ch < nchunk; ch += gridDim.x) {
        int c0 = ch * PB_CHUNK;
        int c1 = c0 + PB_CHUNK; if (c1 > ne) c1 = ne;
        for (int i = threadIdx.x; i < NBUCKET; i += 256) hist[i] = 0;
        __syncthreads();
        for (int e = c0 + threadIdx.x; e < c1; e += 256)
            atomicAdd(&hist[(acol[e] - N_USER_C) >> BSHIFT], 1);
        __syncthreads();
        for (int i = threadIdx.x; i < NBUCKET; i += 256) {
            int h = hist[i];
            base[i] = h ? atomicAdd(&bfill[i], h) : 0;
            hist[i] = 0;                      // reuse as local fill
        }
        __syncthreads();
        for (int e = c0 + threadIdx.x; e < c1; e += 256) {
            int j = acol[e] - N_USER_C;
            int b = j >> BSHIFT;
            int p = atomicAdd(&hist[b], 1);
            staging[boff[b] + base[b] + p] = arow[e] | ((j & 255) << 24);
        }
        __syncthreads();
    }
}

__global__ __launch_bounds__(256) void bucket_finalize_kernel(
        const int* __restrict__ staging, const int* __restrict__ boff,
        int* __restrict__ row_ptr_i, int* __restrict__ csr_col) {
    __shared__ int cnt[256];
    __shared__ int incl[256];
    int b = blockIdx.x, t = threadIdx.x;
    int s0 = boff[b], s1 = boff[b + 1];
    cnt[t] = 0;
    __syncthreads();
    for (int e = s0 + t; e < s1; e += 256)
        atomicAdd(&cnt[((unsigned)staging[e]) >> 24], 1);
    __syncthreads();
    incl[t] = cnt[t];
    __syncthreads();
    for (int o = 1; o < 256; o <<= 1) {
        int v = (t >= o) ? incl[t - o] : 0;
        __syncthreads();
        incl[t] += v;
        __syncthreads();
    }
    int j = (b << BSHIFT) + t;
    if (j < N_ITEM_C) row_ptr_i[j] = s0 + ((t == 0) ? 0 : incl[t - 1]);
    cnt[t] = 0;                               // reuse as per-item fill
    __syncthreads();
    for (int e = s0 + t; e < s1; e += 256) {
        int w = staging[e];
        int jl = ((unsigned)w) >> 24;
        int p = atomicAdd(&cnt[jl], 1);
        int basej = (jl == 0) ? 0 : incl[jl - 1];
        csr_col[s0 + basej + p] = w & 0x00FFFFFF;
    }
}

__global__ void user_rowptr_kernel(const int* __restrict__ arow, int* __restrict__ row_ptr_u,
                                   int ne) {
    int stride = gridDim.x * blockDim.x;
    for (int e = blockIdx.x * blockDim.x + threadIdx.x; e <= ne; e += stride) {
        int prev = (e == 0) ? -1 : arow[e - 1];
        int cur = (e == ne) ? N_USER_C : arow[e];
        for (int r = prev + 1; r <= cur; ++r) row_ptr_u[r] = e;
    }
}

// dinv[r] = (deg + 1e-7)^-0.5 in f64 (matches reference bincount path).
__global__ void dinv_kernel(const int* __restrict__ rpu, const int* __restrict__ rpi,
                            float* __restrict__ dinv) {
    int r = blockIdx.x * blockDim.x + threadIdx.x;
    if (r >= NN_C) return;
    int deg = (r < N_USER_C) ? rpu[r + 1] - rpu[r]
                             : rpi[r - N_USER_C + 1] - rpi[r - N_USER_C];
    double d = (double)deg + 1e-7;
    dinv[r] = (float)(1.0 / sqrt(d));
}

// Mark rows whose final embedding the loss actually reads.
__global__ void flag_kernel(const int* __restrict__ x, int* __restrict__ flags) {
    int idx = blockIdx.x * blockDim.x + threadIdx.x;
    if (idx >= 4096 * 5) return;
    int b = idx / 5, s = idx % 5;
    const int* xb = x + b * 24;
    flags[xb[s * 4]] = 1;
    flags[N_USER_C + xb[s * 4 + 1]] = 1;
}

// f32 weights -> fp16 wtab[NN][64] pre-scaled by dinv (gather-ready).
__global__ __launch_bounds__(256) void conv_kernel(
        const float4* __restrict__ uw, const float4* __restrict__ iw,
        const float* __restrict__ dinv, u32x4* __restrict__ wtab) {
    int stride = gridDim.x * blockDim.x;
    int tot = ND_C / 8;                    /* packs of 8 elems */
    int nu = N_USER_C * D_C / 8;
    for (int i = blockIdx.x * blockDim.x + threadIdx.x; i < tot; i += stride) {
        const float4* s = (i < nu) ? (uw + (size_t)i * 2) : (iw + (size_t)(i - nu) * 2);
        float dv = dinv[i >> 3];
        float4 f0 = s[0], f1 = s[1];
        HP8 o;
        o.h[0] = __float22half2_rn(make_float2(dv * f0.x, dv * f0.y));
        o.h[1] = __float22half2_rn(make_float2(dv * f0.z, dv * f0.w));
        o.h[2] = __float22half2_rn(make_float2(dv * f1.x, dv * f1.y));
        o.h[3] = __float22half2_rn(make_float2(dv * f1.z, dv * f1.w));
        wtab[i] = o.u;
    }
}

// ---- propagation ----------------------------------------------------------
// 8 lanes/row, 16B gathers, val-free: acc += h'[col]. PRESCALE folds dinv_r
// into the stored row (layers whose output is gathered again).

template <bool PRESCALE, bool SPARSE>
__global__ __launch_bounds__(256) void spmv_kernel(
        const __half* __restrict__ hin, __half* __restrict__ hout,
        const int* __restrict__ row_ptr_u, const int* __restrict__ row_ptr_i,
        const int* __restrict__ acol, const int* __restrict__ csr_col,
        const int* __restrict__ flags, const float* __restrict__ dinv) {
    int gid = blockIdx.x * blockDim.x + threadIdx.x;
    int r = gid >> 3;
    int l = gid & 7;
    if (r >= NN_C) return;
    if (SPARSE && flags[r] == 0) return;

    int e0, e1;
    const int* __restrict__ cols;
    if (r < N_USER_C) { e0 = row_ptr_u[r]; e1 = row_ptr_u[r + 1]; cols = acol; }
    else {
        int rr = r - N_USER_C;
        e0 = row_ptr_i[rr]; e1 = row_ptr_i[rr + 1]; cols = csr_col;
    }

    auto srcH = [&](int c) -> const u32x4* {
        return reinterpret_cast<const u32x4*>(hin + (size_t)c * 64 + l * 8);
    };

    float a0[8] = {0}, a1[8] = {0}, a2[8] = {0}, a3[8] = {0};
    auto add8 = [&](float* a, const HP8& p) {
        #pragma unroll
        for (int k = 0; k < 4; ++k) {
            float2 f = __half22float2(p.h[k]);
            a[2 * k] += f.x; a[2 * k + 1] += f.y;
        }
    };

    int e = e0;
    for (; e + 4 <= e1; e += 4) {
        int c0 = cols[e], c1 = cols[e + 1], c2 = cols[e + 2], c3 = cols[e + 3];
        HP8 p0, p1, p2, p3;
        p0.u = *srcH(c0); p1.u = *srcH(c1); p2.u = *srcH(c2); p3.u = *srcH(c3);
        add8(a0, p0); add8(a1, p1); add8(a2, p2); add8(a3, p3);
    }
    for (; e < e1; ++e) {
        HP8 p0; p0.u = *srcH(cols[e]);
        add8(a0, p0);
    }

    float acc[8];
    float ss = 0.f;
    #pragma unroll
    for (int k = 0; k < 8; ++k) {
        acc[k] = (a0[k] + a1[k]) + (a2[k] + a3[k]);
        ss += acc[k] * acc[k];
    }
    ss += __shfl_xor(ss, 1);
    ss += __shfl_xor(ss, 2);
    ss += __shfl_xor(ss, 4);
    float scale = 1.0f / fmaxf(sqrtf(ss), 1e-12f);
    if (PRESCALE) scale *= dinv[r];

    HP8 o;
    #pragma unroll
    for (int k = 0; k < 4; ++k)
        o.h[k] = __float22half2_rn(make_float2(acc[2 * k] * scale, acc[2 * k + 1] * scale));
    *reinterpret_cast<u32x4*>(hout + (size_t)r * 64 + l * 8) = o.u;
}

// ---- losses (two-stage, atomic-free) ---------------------------------------

__global__ void ssq_kernel(const float4* __restrict__ uw, const float4* __restrict__ iw,
                           float2* __restrict__ partial_sq, int n4) {
    __shared__ float s_u[4], s_i[4];
    int stride = gridDim.x * blockDim.x;
    float su = 0.f, si = 0.f;
    int tot = 2 * n4;
    for (int i = blockIdx.x * blockDim.x + threadIdx.x; i < tot; i += stride) {
        float4 v = (i < n4) ? uw[i] : iw[i - n4];
        float d = v.x * v.x + v.y * v.y + v.z * v.z + v.w * v.w;
        if (i < n4) su += d; else si += d;
    }
    #pragma unroll
    for (int o = 1; o < 64; o <<= 1) { su += __shfl_xor(su, o); si += __shfl_xor(si, o); }
    int w = threadIdx.x >> 6;
    if ((threadIdx.x & 63) == 0) { s_u[w] = su; s_i[w] = si; }
    __syncthreads();
    if (threadIdx.x == 0) {
        float tu = s_u[0] + s_u[1] + s_u[2] + s_u[3];
        float ti = s_i[0] + s_i[1] + s_i[2] + s_i[3];
        partial_sq[blockIdx.x] = make_float2(tu, ti);
    }
}

// emb(r) = base + (2*h1' + 1.5*h2')/dinv_r + (4/3)*h3  (h3 stored unscaled)
__global__ void score_kernel(const int* __restrict__ x,
                             const float* __restrict__ uw, const float* __restrict__ iw,
                             const __half* __restrict__ h1, const __half* __restrict__ h2,
                             const __half* __restrict__ h3, const float* __restrict__ dinv,
                             float* __restrict__ partial_loss) {
    __shared__ float s_l[4];
    int wave = threadIdx.x >> 6;
    int lane = threadIdx.x & 63;
    int b = blockIdx.x * 4 + wave;
    const int* xb = x + b * 24;          // (B, S=6, 4) int32

    auto emb = [&](int r) -> float {
        size_t o = (size_t)r * 64 + lane;
        float base = (r < N_USER_C) ? uw[o] : iw[o - (size_t)N_USER_C * 64];
        float rs = 1.0f / dinv[r];
        return base + (2.0f * __half2float(h1[o]) + 1.5f * __half2float(h2[o])) * rs
                    + (4.0f / 3.0f) * __half2float(h3[o]);
    };

    float t = emb(xb[0]) * emb(N_USER_C + xb[1]);
    #pragma unroll
    for (int s = 1; s <= 4; ++s)
        t -= emb(xb[s * 4]) * emb(N_USER_C + xb[s * 4 + 1]);

    #pragma unroll
    for (int o = 1; o < 64; o <<= 1) t += __shfl_xor(t, o);
    if (lane == 0) {
        float sig = 1.0f / (1.0f + expf(-t));
        s_l[wave] = -logf(1e-10f + sig);
    }
    __syncthreads();
    if (threadIdx.x == 0)
        partial_loss[blockIdx.x] = s_l[0] + s_l[1] + s_l[2] + s_l[3];
}

__global__ void final_kernel(const float2* __restrict__ partial_sq,
                             const float* __restrict__ partial_loss,
                             float* __restrict__ out) {
    __shared__ float s_u[4], s_i[4], s_l[4];
    int t = threadIdx.x;
    int w = t >> 6, lane = t & 63;

    float2 p = partial_sq[t];            // SSQ_NBLK == 256 == blockDim
    float su = p.x, si = p.y;
    float lo = 0.f;
    #pragma unroll
    for (int k = 0; k < SCORE_NBLK / 256; ++k) lo += partial_loss[t + k * 256];

    #pragma unroll
    for (int o = 1; o < 64; o <<= 1) {
        su += __shfl_xor(su, o);
        si += __shfl_xor(si, o);
        lo += __shfl_xor(lo, o);
    }
    if (lane == 0) { s_u[w] = su; s_i[w] = si; s_l[w] = lo; }
    __syncthreads();
    if (t == 0) {
        float tu = s_u[0] + s_u[1] + s_u[2] + s_u[3];
        float ti = s_i[0] + s_i[1] + s_i[2] + s_i[3];
        float tl = s_l[0] + s_l[1] + s_l[2] + s_l[3];
        float bpr = tl / 4096.0f;
        float emb_loss = (sqrtf(tu) + sqrtf(ti)) / (float)N_ITEM_C;
        out[0] = bpr + 1e-4f * emb_loss;
    }
}

// ---- launch ---------------------------------------------------------------

extern "C" void kernel_launch(void* const* d_in, const int* in_sizes, int n_in,
                              void* d_out, int out_size, void* d_ws, size_t ws_size,
                              hipStream_t stream) {
    const int*   x    = (const int*)d_in[0];
    const float* uw   = (const float*)d_in[1];
    const float* iw   = (const float*)d_in[2];
    const int*   arow = (const int*)d_in[3];
    const int*   acol = (const int*)d_in[4];
    int nnz = in_sizes[3];
    int ne = nnz / 2;                     // edges per half

    char* ws = (char*)d_ws;
    size_t off = 0;
    auto alloc = [&](size_t bytes) -> void* {
        void* p = ws + off;
        off += bytes;
        off = (off + 255) & ~(size_t)255;
        return p;
    };
    __half* wtab      = (__half*)alloc((size_t)ND_C * 2);
    __half* h1        = (__half*)alloc((size_t)ND_C * 2);
    __half* h2        = (__half*)alloc((size_t)ND_C * 2);
    __half* h3        = (__half*)alloc((size_t)ND_C * 2);
    int*    csr_col   = (int*)alloc((size_t)ne * 4);
    int*    row_ptr_u = (int*)alloc((size_t)(N_USER_C + 1) * 4);
    int*    row_ptr_i = (int*)alloc((size_t)(N_ITEM_C + 1) * 4);
    float*  dinv      = (float*)alloc((size_t)NN_C * 4);
    int*    flags     = (int*)alloc((size_t)NN_C * 4);
    int*    bcnt      = (int*)alloc((size_t)NBUCKET * 4);
    int*    bfill     = (int*)alloc((size_t)NBUCKET * 4);
    int*    boff      = (int*)alloc((size_t)(NBUCKET + 1) * 4);
    float2* psq       = (float2*)alloc((size_t)SSQ_NBLK * 8);
    float*  ploss     = (float*)alloc((size_t)SCORE_NBLK * 4);
    // staging aliases h3 (ne*4 = 6.4MB <= ND_C*2), consumed by bucket_finalize
    // before layer-3 spmv writes h3 (stream-ordered).
    int*    staging   = (int*)h3;

    hipMemsetAsync(bcnt, 0, (size_t)NBUCKET * 4, stream);
    hipMemsetAsync(bfill, 0, (size_t)NBUCKET * 4, stream);
    hipMemsetAsync(flags, 0, (size_t)NN_C * 4, stream);

    const int eb = 256;
    int egrid = (ne + eb - 1) / eb;
    if (egrid > 4096) egrid = 4096;

    bucket_count_kernel<<<256, 256, 0, stream>>>(acol, bcnt, ne);
    bucket_scan_kernel<<<1, 512, 0, stream>>>(bcnt, boff, row_ptr_i, ne);
    int nchunk = (ne + PB_CHUNK - 1) / PB_CHUNK;
    bucket_scatter_kernel<<<nchunk, 256, 0, stream>>>(arow, acol, boff, bfill,
                                                      staging, ne);
    bucket_finalize_kernel<<<NBUCKET, 256, 0, stream>>>(staging, boff, row_ptr_i, csr_col);
    user_rowptr_kernel<<<egrid, eb, 0, stream>>>(arow, row_ptr_u, ne);
    dinv_kernel<<<(NN_C + 255) / 256, 256, 0, stream>>>(row_ptr_u, row_ptr_i, dinv);
    conv_kernel<<<2048, 256, 0, stream>>>((const float4*)uw, (const float4*)iw,
                                          dinv, (u32x4*)wtab);
    flag_kernel<<<80, 256, 0, stream>>>(x, flags);

    int grid = (NN_C * 8 + 255) / 256;   // 6250 blocks
    spmv_kernel<true, false><<<grid, 256, 0, stream>>>(wtab, h1,
        row_ptr_u, row_ptr_i, acol, csr_col, flags, dinv);
    spmv_kernel<true, false><<<grid, 256, 0, stream>>>(h1, h2,
        row_ptr_u, row_ptr_i, acol, csr_col, flags, dinv);
    spmv_kernel<false, true><<<grid, 256, 0, stream>>>(h2, h3,
        row_ptr_u, row_ptr_i, acol, csr_col, flags, dinv);

    ssq_kernel<<<SSQ_NBLK, 256, 0, stream>>>((const float4*)uw, (const float4*)iw,
                                             psq, N_USER_C * D_C / 4);
    score_kernel<<<SCORE_NBLK, 256, 0, stream>>>(x, uw, iw, h1, h2, h3, dinv, ploss);
    final_kernel<<<1, 256, 0, stream>>>(psq, ploss, (float*)d_out);
}

// Round 11
// 340.543 us; speedup vs baseline: 1.3975x; 1.0801x over previous
//
#include <hip/hip_runtime.h>
#include <hip/hip_fp16.h>

#define N_USER_C 100000
#define N_ITEM_C 100000
#define D_C 64
#define NN_C (N_USER_C + N_ITEM_C)
#define ND_C (NN_C * D_C)   /* 12,800,000 elements */

#define BSHIFT 8                                   /* 256 items per bucket */
#define NBUCKET ((N_ITEM_C + 255) >> BSHIFT)       /* 391 */
#define PB_CHUNK 8192

#define CONV_NBLK 1024
#define SCORE_NBLK 1024

typedef unsigned u32x4 __attribute__((ext_vector_type(4)));

union HP8 { u32x4 u; __half2 h[4]; };

// ---- CSR build ------------------------------------------------------------
// Item CSR from FIRST half of edges (second half is the mirror). Col-only
// payload: dinv_c is folded into the gathered table rows, dinv_r cancels in
// row-normalize.

// Fused: bucket histogram (acol) + user row_ptr boundary-detect (arow sorted).
__global__ __launch_bounds__(256) void edge_scan_kernel(
        const int* __restrict__ arow, const int* __restrict__ acol,
        int* __restrict__ bcnt, int* __restrict__ row_ptr_u, int ne) {
    __shared__ int s[NBUCKET];
    for (int i = threadIdx.x; i < NBUCKET; i += 256) s[i] = 0;
    __syncthreads();
    int stride = gridDim.x * blockDim.x;
    for (int e = blockIdx.x * blockDim.x + threadIdx.x; e <= ne; e += stride) {
        if (e < ne) atomicAdd(&s[(acol[e] - N_USER_C) >> BSHIFT], 1);
        int prev = (e == 0) ? -1 : arow[e - 1];
        int cur = (e == ne) ? N_USER_C : arow[e];
        for (int r = prev + 1; r <= cur; ++r) row_ptr_u[r] = e;
    }
    __syncthreads();
    for (int i = threadIdx.x; i < NBUCKET; i += 256)
        if (s[i]) atomicAdd(&bcnt[i], s[i]);
}

__global__ void bucket_scan_kernel(const int* __restrict__ bcnt, int* __restrict__ boff,
                                   int* __restrict__ row_ptr_i, int ne) {
    __shared__ int s[512];
    int t = threadIdx.x;
    s[t] = (t < NBUCKET) ? bcnt[t] : 0;
    __syncthreads();
    for (int o = 1; o < 512; o <<= 1) {
        int v = (t >= o) ? s[t - o] : 0;
        __syncthreads();
        s[t] += v;
        __syncthreads();
    }
    if (t < NBUCKET) boff[t] = (t == 0) ? 0 : s[t - 1];
    if (t == 0) { boff[NBUCKET] = ne; row_ptr_i[N_ITEM_C] = ne; }
}

// staging word = user(17b) | item_local(8b)<<24
__global__ __launch_bounds__(256) void bucket_scatter_kernel(
        const int* __restrict__ arow, const int* __restrict__ acol,
        const int* __restrict__ boff, int* __restrict__ bfill,
        int* __restrict__ staging, int ne) {
    __shared__ int hist[NBUCKET];
    __shared__ int base[NBUCKET];
    int nchunk = (ne + PB_CHUNK - 1) / PB_CHUNK;
    for (int ch = blockIdx.x; ch < nchunk; ch += gridDim.x) {
        int c0 = ch * PB_CHUNK;
        int c1 = c0 + PB_CHUNK; if (c1 > ne) c1 = ne;
        for (int i = threadIdx.x; i < NBUCKET; i += 256) hist[i] = 0;
        __syncthreads();
        for (int e = c0 + threadIdx.x; e < c1; e += 256)
            atomicAdd(&hist[(acol[e] - N_USER_C) >> BSHIFT], 1);
        __syncthreads();
        for (int i = threadIdx.x; i < NBUCKET; i += 256) {
            int h = hist[i];
            base[i] = h ? atomicAdd(&bfill[i], h) : 0;
            hist[i] = 0;                      // reuse as local fill
        }
        __syncthreads();
        for (int e = c0 + threadIdx.x; e < c1; e += 256) {
            int j = acol[e] - N_USER_C;
            int b = j >> BSHIFT;
            int p = atomicAdd(&hist[b], 1);
            staging[boff[b] + base[b] + p] = arow[e] | ((j & 255) << 24);
        }
        __syncthreads();
    }
}

__global__ __launch_bounds__(256) void bucket_finalize_kernel(
        const int* __restrict__ staging, const int* __restrict__ boff,
        int* __restrict__ row_ptr_i, int* __restrict__ csr_col) {
    __shared__ int cnt[256];
    __shared__ int incl[256];
    int b = blockIdx.x, t = threadIdx.x;
    int s0 = boff[b], s1 = boff[b + 1];
    cnt[t] = 0;
    __syncthreads();
    for (int e = s0 + t; e < s1; e += 256)
        atomicAdd(&cnt[((unsigned)staging[e]) >> 24], 1);
    __syncthreads();
    incl[t] = cnt[t];
    __syncthreads();
    for (int o = 1; o < 256; o <<= 1) {
        int v = (t >= o) ? incl[t - o] : 0;
        __syncthreads();
        incl[t] += v;
        __syncthreads();
    }
    int j = (b << BSHIFT) + t;
    if (j < N_ITEM_C) row_ptr_i[j] = s0 + ((t == 0) ? 0 : incl[t - 1]);
    cnt[t] = 0;                               // reuse as per-item fill
    __syncthreads();
    for (int e = s0 + t; e < s1; e += 256) {
        int w = staging[e];
        int jl = ((unsigned)w) >> 24;
        int p = atomicAdd(&cnt[jl], 1);
        int basej = (jl == 0) ? 0 : incl[jl - 1];
        csr_col[s0 + basej + p] = w & 0x00FFFFFF;
    }
}

// dinv[r] = (deg + 1e-7)^-0.5 (f64, matching reference); fused loss-row flags.
__global__ void dinv_flag_kernel(const int* __restrict__ rpu, const int* __restrict__ rpi,
                                 const int* __restrict__ x,
                                 float* __restrict__ dinv, int* __restrict__ flags) {
    int r = blockIdx.x * blockDim.x + threadIdx.x;
    if (r < NN_C) {
        int deg = (r < N_USER_C) ? rpu[r + 1] - rpu[r]
                                 : rpi[r - N_USER_C + 1] - rpi[r - N_USER_C];
        double d = (double)deg + 1e-7;
        dinv[r] = (float)(1.0 / sqrt(d));
    }
    if (r < 4096 * 5) {
        int b = r / 5, s = r % 5;
        const int* xb = x + b * 24;
        flags[xb[s * 4]] = 1;
        flags[N_USER_C + xb[s * 4 + 1]] = 1;
    }
}

// f32 weights -> fp16 wtab[NN][64] pre-scaled by dinv; fused ssq partials
// (sum-of-squares of the RAW weights).
__global__ __launch_bounds__(256) void conv_ssq_kernel(
        const float4* __restrict__ uw, const float4* __restrict__ iw,
        const float* __restrict__ dinv, u32x4* __restrict__ wtab,
        float2* __restrict__ partial_sq) {
    __shared__ float s_u[4], s_i[4];
    int stride = gridDim.x * blockDim.x;
    int tot = ND_C / 8;                    /* packs of 8 elems */
    int nu = N_USER_C * D_C / 8;
    float su = 0.f, si = 0.f;
    for (int i = blockIdx.x * blockDim.x + threadIdx.x; i < tot; i += stride) {
        bool user = i < nu;
        const float4* s = user ? (uw + (size_t)i * 2) : (iw + (size_t)(i - nu) * 2);
        float4 f0 = s[0], f1 = s[1];
        float d = f0.x * f0.x + f0.y * f0.y + f0.z * f0.z + f0.w * f0.w
                + f1.x * f1.x + f1.y * f1.y + f1.z * f1.z + f1.w * f1.w;
        if (user) su += d; else si += d;
        float dv = dinv[i >> 3];
        HP8 o;
        o.h[0] = __float22half2_rn(make_float2(dv * f0.x, dv * f0.y));
        o.h[1] = __float22half2_rn(make_float2(dv * f0.z, dv * f0.w));
        o.h[2] = __float22half2_rn(make_float2(dv * f1.x, dv * f1.y));
        o.h[3] = __float22half2_rn(make_float2(dv * f1.z, dv * f1.w));
        wtab[i] = o.u;
    }
    #pragma unroll
    for (int o = 1; o < 64; o <<= 1) { su += __shfl_xor(su, o); si += __shfl_xor(si, o); }
    int w = threadIdx.x >> 6;
    if ((threadIdx.x & 63) == 0) { s_u[w] = su; s_i[w] = si; }
    __syncthreads();
    if (threadIdx.x == 0)
        partial_sq[blockIdx.x] = make_float2(s_u[0] + s_u[1] + s_u[2] + s_u[3],
                                             s_i[0] + s_i[1] + s_i[2] + s_i[3]);
}

// ---- propagation ----------------------------------------------------------
// 8 lanes/row, 16B gathers, val-free: acc += h'[col]. 2 accumulator sets,
// 4 loads in flight. PRESCALE folds dinv_r into stored row.

template <bool PRESCALE, bool SPARSE>
__global__ __launch_bounds__(256, 4) void spmv_kernel(
        const __half* __restrict__ hin, __half* __restrict__ hout,
        const int* __restrict__ row_ptr_u, const int* __restrict__ row_ptr_i,
        const int* __restrict__ acol, const int* __restrict__ csr_col,
        const int* __restrict__ flags, const float* __restrict__ dinv) {
    int gid = blockIdx.x * blockDim.x + threadIdx.x;
    int r = gid >> 3;
    int l = gid & 7;
    if (r >= NN_C) return;
    if (SPARSE && flags[r] == 0) return;

    int e0, e1;
    const int* __restrict__ cols;
    if (r < N_USER_C) { e0 = row_ptr_u[r]; e1 = row_ptr_u[r + 1]; cols = acol; }
    else {
        int rr = r - N_USER_C;
        e0 = row_ptr_i[rr]; e1 = row_ptr_i[rr + 1]; cols = csr_col;
    }

    auto srcH = [&](int c) -> const u32x4* {
        return reinterpret_cast<const u32x4*>(hin + (size_t)c * 64 + l * 8);
    };

    float a0[8] = {0}, a1[8] = {0};
    auto add8 = [&](float* a, const HP8& p) {
        #pragma unroll
        for (int k = 0; k < 4; ++k) {
            float2 f = __half22float2(p.h[k]);
            a[2 * k] += f.x; a[2 * k + 1] += f.y;
        }
    };

    int e = e0;
    for (; e + 4 <= e1; e += 4) {
        int c0 = cols[e], c1 = cols[e + 1], c2 = cols[e + 2], c3 = cols[e + 3];
        HP8 p0, p1, p2, p3;
        p0.u = *srcH(c0); p1.u = *srcH(c1); p2.u = *srcH(c2); p3.u = *srcH(c3);
        add8(a0, p0); add8(a1, p1); add8(a0, p2); add8(a1, p3);
    }
    for (; e < e1; ++e) {
        HP8 p0; p0.u = *srcH(cols[e]);
        add8(a0, p0);
    }

    float acc[8];
    float ss = 0.f;
    #pragma unroll
    for (int k = 0; k < 8; ++k) {
        acc[k] = a0[k] + a1[k];
        ss += acc[k] * acc[k];
    }
    ss += __shfl_xor(ss, 1);
    ss += __shfl_xor(ss, 2);
    ss += __shfl_xor(ss, 4);
    float scale = 1.0f / fmaxf(sqrtf(ss), 1e-12f);
    if (PRESCALE) scale *= dinv[r];

    HP8 o;
    #pragma unroll
    for (int k = 0; k < 4; ++k)
        o.h[k] = __float22half2_rn(make_float2(acc[2 * k] * scale, acc[2 * k + 1] * scale));
    *reinterpret_cast<u32x4*>(hout + (size_t)r * 64 + l * 8) = o.u;
}

// ---- loss ------------------------------------------------------------------

// emb(r) = base + (2*h1' + 1.5*h2')/dinv_r + (4/3)*h3  (h3 stored unscaled)
__global__ void score_kernel(const int* __restrict__ x,
                             const float* __restrict__ uw, const float* __restrict__ iw,
                             const __half* __restrict__ h1, const __half* __restrict__ h2,
                             const __half* __restrict__ h3, const float* __restrict__ dinv,
                             float* __restrict__ partial_loss) {
    __shared__ float s_l[4];
    int wave = threadIdx.x >> 6;
    int lane = threadIdx.x & 63;
    int b = blockIdx.x * 4 + wave;
    const int* xb = x + b * 24;          // (B, S=6, 4) int32

    auto emb = [&](int r) -> float {
        size_t o = (size_t)r * 64 + lane;
        float base = (r < N_USER_C) ? uw[o] : iw[o - (size_t)N_USER_C * 64];
        float rs = 1.0f / dinv[r];
        return base + (2.0f * __half2float(h1[o]) + 1.5f * __half2float(h2[o])) * rs
                    + (4.0f / 3.0f) * __half2float(h3[o]);
    };

    float t = emb(xb[0]) * emb(N_USER_C + xb[1]);
    #pragma unroll
    for (int s = 1; s <= 4; ++s)
        t -= emb(xb[s * 4]) * emb(N_USER_C + xb[s * 4 + 1]);

    #pragma unroll
    for (int o = 1; o < 64; o <<= 1) t += __shfl_xor(t, o);
    if (lane == 0) {
        float sig = 1.0f / (1.0f + expf(-t));
        s_l[wave] = -logf(1e-10f + sig);
    }
    __syncthreads();
    if (threadIdx.x == 0)
        partial_loss[blockIdx.x] = s_l[0] + s_l[1] + s_l[2] + s_l[3];
}

__global__ void final_kernel(const float2* __restrict__ partial_sq,
                             const float* __restrict__ partial_loss,
                             float* __restrict__ out) {
    __shared__ float s_u[4], s_i[4], s_l[4];
    int t = threadIdx.x;
    int w = t >> 6, lane = t & 63;

    float su = 0.f, si = 0.f, lo = 0.f;
    #pragma unroll
    for (int k = 0; k < CONV_NBLK / 256; ++k) {
        float2 p = partial_sq[t + k * 256];
        su += p.x; si += p.y;
    }
    #pragma unroll
    for (int k = 0; k < SCORE_NBLK / 256; ++k) lo += partial_loss[t + k * 256];

    #pragma unroll
    for (int o = 1; o < 64; o <<= 1) {
        su += __shfl_xor(su, o);
        si += __shfl_xor(si, o);
        lo += __shfl_xor(lo, o);
    }
    if (lane == 0) { s_u[w] = su; s_i[w] = si; s_l[w] = lo; }
    __syncthreads();
    if (t == 0) {
        float tu = s_u[0] + s_u[1] + s_u[2] + s_u[3];
        float ti = s_i[0] + s_i[1] + s_i[2] + s_i[3];
        float tl = s_l[0] + s_l[1] + s_l[2] + s_l[3];
        float bpr = tl / 4096.0f;
        float emb_loss = (sqrtf(tu) + sqrtf(ti)) / (float)N_ITEM_C;
        out[0] = bpr + 1e-4f * emb_loss;
    }
}

// ---- launch ---------------------------------------------------------------

extern "C" void kernel_launch(void* const* d_in, const int* in_sizes, int n_in,
                              void* d_out, int out_size, void* d_ws, size_t ws_size,
                              hipStream_t stream) {
    const int*   x    = (const int*)d_in[0];
    const float* uw   = (const float*)d_in[1];
    const float* iw   = (const float*)d_in[2];
    const int*   arow = (const int*)d_in[3];
    const int*   acol = (const int*)d_in[4];
    int nnz = in_sizes[3];
    int ne = nnz / 2;                     // edges per half

    char* ws = (char*)d_ws;
    size_t off = 0;
    auto alloc = [&](size_t bytes) -> void* {
        void* p = ws + off;
        off += bytes;
        off = (off + 255) & ~(size_t)255;
        return p;
    };
    __half* wtab      = (__half*)alloc((size_t)ND_C * 2);
    __half* h1        = (__half*)alloc((size_t)ND_C * 2);
    __half* h2        = (__half*)alloc((size_t)ND_C * 2);
    __half* h3        = (__half*)alloc((size_t)ND_C * 2);
    int*    csr_col   = (int*)alloc((size_t)ne * 4);
    int*    row_ptr_u = (int*)alloc((size_t)(N_USER_C + 1) * 4);
    int*    row_ptr_i = (int*)alloc((size_t)(N_ITEM_C + 1) * 4);
    float*  dinv      = (float*)alloc((size_t)NN_C * 4);
    int*    flags     = (int*)alloc((size_t)NN_C * 4);
    int*    bmem      = (int*)alloc((size_t)2 * NBUCKET * 4);  // bcnt | bfill
    int*    boff      = (int*)alloc((size_t)(NBUCKET + 1) * 4);
    float2* psq       = (float2*)alloc((size_t)CONV_NBLK * 8);
    float*  ploss     = (float*)alloc((size_t)SCORE_NBLK * 4);
    int*    bcnt      = bmem;
    int*    bfill     = bmem + NBUCKET;
    // staging aliases h3 (ne*4 = 6.4MB <= ND_C*2), consumed by bucket_finalize
    // before layer-3 spmv writes h3 (stream-ordered).
    int*    staging   = (int*)h3;

    hipMemsetAsync(bmem, 0, (size_t)2 * NBUCKET * 4, stream);
    hipMemsetAsync(flags, 0, (size_t)NN_C * 4, stream);

    edge_scan_kernel<<<256, 256, 0, stream>>>(arow, acol, bcnt, row_ptr_u, ne);
    bucket_scan_kernel<<<1, 512, 0, stream>>>(bcnt, boff, row_ptr_i, ne);
    int nchunk = (ne + PB_CHUNK - 1) / PB_CHUNK;
    bucket_scatter_kernel<<<nchunk, 256, 0, stream>>>(arow, acol, boff, bfill,
                                                      staging, ne);
    bucket_finalize_kernel<<<NBUCKET, 256, 0, stream>>>(staging, boff, row_ptr_i, csr_col);
    dinv_flag_kernel<<<(NN_C + 255) / 256, 256, 0, stream>>>(row_ptr_u, row_ptr_i,
                                                             x, dinv, flags);
    conv_ssq_kernel<<<CONV_NBLK, 256, 0, stream>>>((const float4*)uw, (const float4*)iw,
                                                   dinv, (u32x4*)wtab, psq);

    int grid = (NN_C * 8 + 255) / 256;   // 6250 blocks
    spmv_kernel<true, false><<<grid, 256, 0, stream>>>(wtab, h1,
        row_ptr_u, row_ptr_i, acol, csr_col, flags, dinv);
    spmv_kernel<true, false><<<grid, 256, 0, stream>>>(h1, h2,
        row_ptr_u, row_ptr_i, acol, csr_col, flags, dinv);
    spmv_kernel<false, true><<<grid, 256, 0, stream>>>(h2, h3,
        row_ptr_u, row_ptr_i, acol, csr_col, flags, dinv);

    score_kernel<<<SCORE_NBLK, 256, 0, stream>>>(x, uw, iw, h1, h2, h3, dinv, ploss);
    final_kernel<<<1, 256, 0, stream>>>(psq, ploss, (float*)d_out);
}

// Round 12
// 318.783 us; speedup vs baseline: 1.4929x; 1.0683x over previous
//
#include <hip/hip_runtime.h>
#include <hip/hip_fp16.h>

#define N_USER_C 100000
#define N_ITEM_C 100000
#define D_C 64
#define NN_C (N_USER_C + N_ITEM_C)
#define ND_C (NN_C * D_C)   /* 12,800,000 elements */

#define BSHIFT 8                                   /* 256 items per bucket */
#define NBUCKET ((N_ITEM_C + 255) >> BSHIFT)       /* 391 */
#define PB_CHUNK 8192
#define BCAP 8192          /* padded slots per bucket (mean 4090, 64 sigma) */

#define CONV_NBLK 1024
#define SCORE_NBLK 1024
#define NWORK_MAX (4096 * 5 * 2)   /* 40960 */

typedef unsigned u32x4 __attribute__((ext_vector_type(4)));

union HP8 { u32x4 u; __half2 h[4]; };

// ---- CSR build (one-pass padded counting sort) -----------------------------
// Item CSR from FIRST half of edges (second half is the mirror). Col-only
// payload: dinv_c folded into gathered rows, dinv_r cancels in row-normalize.
// staging word = user(17b) | item_local(8b)<<24

__global__ __launch_bounds__(256) void scatter_kernel(
        const int* __restrict__ arow, const int* __restrict__ acol,
        int* __restrict__ bfill, int* __restrict__ staging,
        int* __restrict__ row_ptr_u, int ne) {
    __shared__ int hist[NBUCKET];
    __shared__ int base[NBUCKET];
    if (blockIdx.x == 0 && threadIdx.x == 0) {
        int last = arow[ne - 1];
        for (int r = last + 1; r <= N_USER_C; ++r) row_ptr_u[r] = ne;
    }
    int nchunk = (ne + PB_CHUNK - 1) / PB_CHUNK;
    for (int ch = blockIdx.x; ch < nchunk; ch += gridDim.x) {
        int c0 = ch * PB_CHUNK;
        int c1 = c0 + PB_CHUNK; if (c1 > ne) c1 = ne;
        for (int i = threadIdx.x; i < NBUCKET; i += 256) hist[i] = 0;
        __syncthreads();
        for (int e = c0 + threadIdx.x; e < c1; e += 256) {
            atomicAdd(&hist[(acol[e] - N_USER_C) >> BSHIFT], 1);
            int prev = (e == 0) ? -1 : arow[e - 1];
            int cur = arow[e];
            for (int r = prev + 1; r <= cur; ++r) row_ptr_u[r] = e;
        }
        __syncthreads();
        for (int i = threadIdx.x; i < NBUCKET; i += 256) {
            int h = hist[i];
            base[i] = h ? atomicAdd(&bfill[i], h) : 0;
            hist[i] = 0;                      // reuse as local fill
        }
        __syncthreads();
        for (int e = c0 + threadIdx.x; e < c1; e += 256) {
            int j = acol[e] - N_USER_C;
            int b = j >> BSHIFT;
            int p = atomicAdd(&hist[b], 1);
            staging[b * BCAP + base[b] + p] = arow[e] | ((j & 255) << 24);
        }
        __syncthreads();
    }
}

// One block per bucket: per-item LDS histogram + scan -> packed row_ptr
// (start|cnt<<22, start < 391*8192 fits 22b, cnt << 1024), then in-L2
// scatter into the padded CSR region.
__global__ __launch_bounds__(256) void finalize_kernel(
        const int* __restrict__ staging, const int* __restrict__ bfill,
        int* __restrict__ rpi_packed, int* __restrict__ csr_col) {
    __shared__ int cnt[256];
    __shared__ int incl[256];
    int b = blockIdx.x, t = threadIdx.x;
    int n = bfill[b];
    int s0 = b * BCAP;
    cnt[t] = 0;
    __syncthreads();
    for (int e = t; e < n; e += 256)
        atomicAdd(&cnt[((unsigned)staging[s0 + e]) >> 24], 1);
    __syncthreads();
    incl[t] = cnt[t];
    __syncthreads();
    for (int o = 1; o < 256; o <<= 1) {
        int v = (t >= o) ? incl[t - o] : 0;
        __syncthreads();
        incl[t] += v;
        __syncthreads();
    }
    int excl = (t == 0) ? 0 : incl[t - 1];
    int mycnt = incl[t] - excl;
    int j = (b << BSHIFT) + t;
    if (j < N_ITEM_C) rpi_packed[j] = (s0 + excl) | (mycnt << 22);
    cnt[t] = 0;                               // reuse as per-item fill
    __syncthreads();
    for (int e = t; e < n; e += 256) {
        int w = staging[s0 + e];
        int jl = ((unsigned)w) >> 24;
        int p = atomicAdd(&cnt[jl], 1);
        int basej = (jl == 0) ? 0 : incl[jl - 1];
        csr_col[s0 + basej + p] = w & 0x00FFFFFF;
    }
}

// dinv[r] = (deg+1e-7)^-0.5 (f64, matches reference); fused worklist append
// of loss-referenced rows (block-aggregated; duplicates benign).
__global__ void dinv_work_kernel(const int* __restrict__ rpu,
                                 const int* __restrict__ rpi_packed,
                                 const int* __restrict__ x,
                                 float* __restrict__ dinv,
                                 int* __restrict__ wl, int* __restrict__ wl_cnt) {
    __shared__ int lcnt, lbase;
    int r = blockIdx.x * 256 + threadIdx.x;
    if (r < NN_C) {
        int deg = (r < N_USER_C) ? rpu[r + 1] - rpu[r]
                                 : (int)(((unsigned)rpi_packed[r - N_USER_C]) >> 22);
        double d = (double)deg + 1e-7;
        dinv[r] = (float)(1.0 / sqrt(d));
    }
    if (threadIdx.x == 0) lcnt = 0;
    __syncthreads();
    int rows[2]; int n = 0, loc = 0;
    if (r < 4096 * 5) {
        int b = r / 5, s = r % 5;
        const int* xb = x + b * 24;
        rows[0] = xb[s * 4];
        rows[1] = N_USER_C + xb[s * 4 + 1];
        n = 2;
        loc = atomicAdd(&lcnt, 2);
    }
    __syncthreads();
    if (threadIdx.x == 0) lbase = lcnt ? atomicAdd(wl_cnt, lcnt) : 0;
    __syncthreads();
    for (int i = 0; i < n; ++i) wl[lbase + loc + i] = rows[i];
}

// f32 weights -> fp16 wtab[NN][64] pre-scaled by dinv; fused ssq partials
// (sum-of-squares of the RAW weights).
__global__ __launch_bounds__(256) void conv_ssq_kernel(
        const float4* __restrict__ uw, const float4* __restrict__ iw,
        const float* __restrict__ dinv, u32x4* __restrict__ wtab,
        float2* __restrict__ partial_sq) {
    __shared__ float s_u[4], s_i[4];
    int stride = gridDim.x * blockDim.x;
    int tot = ND_C / 8;                    /* packs of 8 elems */
    int nu = N_USER_C * D_C / 8;
    float su = 0.f, si = 0.f;
    for (int i = blockIdx.x * blockDim.x + threadIdx.x; i < tot; i += stride) {
        bool user = i < nu;
        const float4* s = user ? (uw + (size_t)i * 2) : (iw + (size_t)(i - nu) * 2);
        float4 f0 = s[0], f1 = s[1];
        float d = f0.x * f0.x + f0.y * f0.y + f0.z * f0.z + f0.w * f0.w
                + f1.x * f1.x + f1.y * f1.y + f1.z * f1.z + f1.w * f1.w;
        if (user) su += d; else si += d;
        float dv = dinv[i >> 3];
        HP8 o;
        o.h[0] = __float22half2_rn(make_float2(dv * f0.x, dv * f0.y));
        o.h[1] = __float22half2_rn(make_float2(dv * f0.z, dv * f0.w));
        o.h[2] = __float22half2_rn(make_float2(dv * f1.x, dv * f1.y));
        o.h[3] = __float22half2_rn(make_float2(dv * f1.z, dv * f1.w));
        wtab[i] = o.u;
    }
    #pragma unroll
    for (int o = 1; o < 64; o <<= 1) { su += __shfl_xor(su, o); si += __shfl_xor(si, o); }
    int w = threadIdx.x >> 6;
    if ((threadIdx.x & 63) == 0) { s_u[w] = su; s_i[w] = si; }
    __syncthreads();
    if (threadIdx.x == 0)
        partial_sq[blockIdx.x] = make_float2(s_u[0] + s_u[1] + s_u[2] + s_u[3],
                                             s_i[0] + s_i[1] + s_i[2] + s_i[3]);
}

// ---- propagation ----------------------------------------------------------
// 8 lanes/row, 16B gathers, val-free: acc += h'[col]. WORK: row from worklist.
// PRESCALE folds dinv_r into stored row.

template <bool PRESCALE, bool WORK>
__global__ __launch_bounds__(256, 4) void spmv_kernel(
        const __half* __restrict__ hin, __half* __restrict__ hout,
        const int* __restrict__ row_ptr_u, const int* __restrict__ rpi_packed,
        const int* __restrict__ acol, const int* __restrict__ csr_col,
        const int* __restrict__ wl, const int* __restrict__ wl_cnt,
        const float* __restrict__ dinv) {
    int gid = blockIdx.x * blockDim.x + threadIdx.x;
    int slot = gid >> 3;
    int l = gid & 7;
    int r;
    if (WORK) {
        if (slot >= *wl_cnt) return;
        r = wl[slot];
    } else {
        r = slot;
        if (r >= NN_C) return;
    }

    int e0, e1;
    const int* __restrict__ cols;
    if (r < N_USER_C) { e0 = row_ptr_u[r]; e1 = row_ptr_u[r + 1]; cols = acol; }
    else {
        unsigned pk = (unsigned)rpi_packed[r - N_USER_C];
        e0 = pk & 0x3FFFFF; e1 = e0 + (pk >> 22); cols = csr_col;
    }

    auto srcH = [&](int c) -> const u32x4* {
        return reinterpret_cast<const u32x4*>(hin + (size_t)c * 64 + l * 8);
    };

    float a0[8] = {0}, a1[8] = {0};
    auto add8 = [&](float* a, const HP8& p) {
        #pragma unroll
        for (int k = 0; k < 4; ++k) {
            float2 f = __half22float2(p.h[k]);
            a[2 * k] += f.x; a[2 * k + 1] += f.y;
        }
    };

    int e = e0;
    for (; e + 4 <= e1; e += 4) {
        int c0 = cols[e], c1 = cols[e + 1], c2 = cols[e + 2], c3 = cols[e + 3];
        HP8 p0, p1, p2, p3;
        p0.u = *srcH(c0); p1.u = *srcH(c1); p2.u = *srcH(c2); p3.u = *srcH(c3);
        add8(a0, p0); add8(a1, p1); add8(a0, p2); add8(a1, p3);
    }
    for (; e < e1; ++e) {
        HP8 p0; p0.u = *srcH(cols[e]);
        add8(a0, p0);
    }

    float acc[8];
    float ss = 0.f;
    #pragma unroll
    for (int k = 0; k < 8; ++k) {
        acc[k] = a0[k] + a1[k];
        ss += acc[k] * acc[k];
    }
    ss += __shfl_xor(ss, 1);
    ss += __shfl_xor(ss, 2);
    ss += __shfl_xor(ss, 4);
    float scale = 1.0f / fmaxf(sqrtf(ss), 1e-12f);
    if (PRESCALE) scale *= dinv[r];

    HP8 o;
    #pragma unroll
    for (int k = 0; k < 4; ++k)
        o.h[k] = __float22half2_rn(make_float2(acc[2 * k] * scale, acc[2 * k + 1] * scale));
    *reinterpret_cast<u32x4*>(hout + (size_t)r * 64 + l * 8) = o.u;
}

// ---- loss ------------------------------------------------------------------

// emb(r) = base + (2*h1' + 1.5*h2')/dinv_r + (4/3)*h3  (h3 stored unscaled)
__global__ void score_kernel(const int* __restrict__ x,
                             const float* __restrict__ uw, const float* __restrict__ iw,
                             const __half* __restrict__ h1, const __half* __restrict__ h2,
                             const __half* __restrict__ h3, const float* __restrict__ dinv,
                             float* __restrict__ partial_loss) {
    __shared__ float s_l[4];
    int wave = threadIdx.x >> 6;
    int lane = threadIdx.x & 63;
    int b = blockIdx.x * 4 + wave;
    const int* xb = x + b * 24;          // (B, S=6, 4) int32

    auto emb = [&](int r) -> float {
        size_t o = (size_t)r * 64 + lane;
        float base = (r < N_USER_C) ? uw[o] : iw[o - (size_t)N_USER_C * 64];
        float rs = 1.0f / dinv[r];
        return base + (2.0f * __half2float(h1[o]) + 1.5f * __half2float(h2[o])) * rs
                    + (4.0f / 3.0f) * __half2float(h3[o]);
    };

    float t = emb(xb[0]) * emb(N_USER_C + xb[1]);
    #pragma unroll
    for (int s = 1; s <= 4; ++s)
        t -= emb(xb[s * 4]) * emb(N_USER_C + xb[s * 4 + 1]);

    #pragma unroll
    for (int o = 1; o < 64; o <<= 1) t += __shfl_xor(t, o);
    if (lane == 0) {
        float sig = 1.0f / (1.0f + expf(-t));
        s_l[wave] = -logf(1e-10f + sig);
    }
    __syncthreads();
    if (threadIdx.x == 0)
        partial_loss[blockIdx.x] = s_l[0] + s_l[1] + s_l[2] + s_l[3];
}

__global__ void final_kernel(const float2* __restrict__ partial_sq,
                             const float* __restrict__ partial_loss,
                             float* __restrict__ out) {
    __shared__ float s_u[4], s_i[4], s_l[4];
    int t = threadIdx.x;
    int w = t >> 6, lane = t & 63;

    float su = 0.f, si = 0.f, lo = 0.f;
    #pragma unroll
    for (int k = 0; k < CONV_NBLK / 256; ++k) {
        float2 p = partial_sq[t + k * 256];
        su += p.x; si += p.y;
    }
    #pragma unroll
    for (int k = 0; k < SCORE_NBLK / 256; ++k) lo += partial_loss[t + k * 256];

    #pragma unroll
    for (int o = 1; o < 64; o <<= 1) {
        su += __shfl_xor(su, o);
        si += __shfl_xor(si, o);
        lo += __shfl_xor(lo, o);
    }
    if (lane == 0) { s_u[w] = su; s_i[w] = si; s_l[w] = lo; }
    __syncthreads();
    if (t == 0) {
        float tu = s_u[0] + s_u[1] + s_u[2] + s_u[3];
        float ti = s_i[0] + s_i[1] + s_i[2] + s_i[3];
        float tl = s_l[0] + s_l[1] + s_l[2] + s_l[3];
        float bpr = tl / 4096.0f;
        float emb_loss = (sqrtf(tu) + sqrtf(ti)) / (float)N_ITEM_C;
        out[0] = bpr + 1e-4f * emb_loss;
    }
}

// ---- launch ---------------------------------------------------------------

extern "C" void kernel_launch(void* const* d_in, const int* in_sizes, int n_in,
                              void* d_out, int out_size, void* d_ws, size_t ws_size,
                              hipStream_t stream) {
    const int*   x    = (const int*)d_in[0];
    const float* uw   = (const float*)d_in[1];
    const float* iw   = (const float*)d_in[2];
    const int*   arow = (const int*)d_in[3];
    const int*   acol = (const int*)d_in[4];
    int nnz = in_sizes[3];
    int ne = nnz / 2;                     // edges per half

    char* ws = (char*)d_ws;
    size_t off = 0;
    auto alloc = [&](size_t bytes) -> void* {
        void* p = ws + off;
        off += bytes;
        off = (off + 255) & ~(size_t)255;
        return p;
    };
    __half* wtab       = (__half*)alloc((size_t)ND_C * 2);
    __half* h1         = (__half*)alloc((size_t)ND_C * 2);
    __half* h2         = (__half*)alloc((size_t)ND_C * 2);
    __half* h3         = (__half*)alloc((size_t)ND_C * 2);
    int*    csr_col    = (int*)alloc((size_t)NBUCKET * BCAP * 4);   /* padded */
    int*    row_ptr_u  = (int*)alloc((size_t)(N_USER_C + 1) * 4);
    int*    rpi_packed = (int*)alloc((size_t)N_ITEM_C * 4);
    float*  dinv       = (float*)alloc((size_t)NN_C * 4);
    int*    bmem       = (int*)alloc((size_t)(NBUCKET + 1) * 4);  // bfill | wl_cnt
    int*    wl         = (int*)alloc((size_t)NWORK_MAX * 4);
    float2* psq        = (float2*)alloc((size_t)CONV_NBLK * 8);
    float*  ploss      = (float*)alloc((size_t)SCORE_NBLK * 4);
    int*    bfill      = bmem;
    int*    wl_cnt     = bmem + NBUCKET;
    // staging aliases h3 (391*8192*4 = 12.8MB <= ND_C*2 = 25.6MB); consumed by
    // finalize before layer-3 spmv writes h3 (stream-ordered).
    int*    staging    = (int*)h3;

    hipMemsetAsync(bmem, 0, (size_t)(NBUCKET + 1) * 4, stream);

    int nchunk = (ne + PB_CHUNK - 1) / PB_CHUNK;
    scatter_kernel<<<nchunk, 256, 0, stream>>>(arow, acol, bfill, staging,
                                               row_ptr_u, ne);
    finalize_kernel<<<NBUCKET, 256, 0, stream>>>(staging, bfill, rpi_packed, csr_col);
    dinv_work_kernel<<<(NN_C + 255) / 256, 256, 0, stream>>>(row_ptr_u, rpi_packed,
                                                             x, dinv, wl, wl_cnt);
    conv_ssq_kernel<<<CONV_NBLK, 256, 0, stream>>>((const float4*)uw, (const float4*)iw,
                                                   dinv, (u32x4*)wtab, psq);

    int grid = (NN_C * 8 + 255) / 256;        // 6250 blocks
    int wgrid = (NWORK_MAX * 8 + 255) / 256;  // 1280 blocks
    spmv_kernel<true, false><<<grid, 256, 0, stream>>>(wtab, h1,
        row_ptr_u, rpi_packed, acol, csr_col, wl, wl_cnt, dinv);
    spmv_kernel<true, false><<<grid, 256, 0, stream>>>(h1, h2,
        row_ptr_u, rpi_packed, acol, csr_col, wl, wl_cnt, dinv);
    spmv_kernel<false, true><<<wgrid, 256, 0, stream>>>(h2, h3,
        row_ptr_u, rpi_packed, acol, csr_col, wl, wl_cnt, dinv);

    score_kernel<<<SCORE_NBLK, 256, 0, stream>>>(x, uw, iw, h1, h2, h3, dinv, ploss);
    final_kernel<<<1, 256, 0, stream>>>(psq, ploss, (float*)d_out);
}